// Round 8
// baseline (151.254 us; speedup 1.0000x reference)
//
#include <hip/hip_runtime.h>
#include <stdint.h>

#define NFRAMES 2
#define NT 4           // NTYPES
#define BLK 256        // block size (4 waves)
#define NJ 64          // j-chunks of 64 atoms (nloc/NJ == 64)
#define IPT 2          // atoms per thread

// broadcast lane l's value across the wave via readlane (pure VALU, exact bits)
__device__ __forceinline__ float bcast_f(float v, int l) {
    return __uint_as_float(__builtin_amdgcn_readlane(__float_as_uint(v), l));
}

// ---------------------------------------------------------------------------
// one pair interaction; bit-exact r2 vs numpy ((dx^2+dy^2)+dz^2, no contract)
// ---------------------------------------------------------------------------
template <bool SELFCHK>
__device__ __forceinline__ void do_pair(float cx, float cy, float cz, unsigned sval,
                                        int j, int i,
                                        float xi, float yi, float zi,
                                        float& mm, unsigned& cc) {
#pragma clang fp contract(off)
    float dx = cx - xi;
    float dy = cy - yi;
    float dz = cz - zi;
    float xx = dx * dx;
    float yy = dy * dy;
    float zz = dz * dz;
    float r2 = (xx + yy) + zz;
    bool self = SELFCHK && (j == i);
    mm = fminf(mm, self ? __builtin_inff() : r2);
    bool near = (r2 < 36.0f) && !self;
    cc += near ? sval : 0u;
}

// ---------------------------------------------------------------------------
// memory-free inner loop over a 64-atom register chunk
// ---------------------------------------------------------------------------
template <bool SELFCHK>
__device__ __forceinline__ void chunk_loop(float bx, float by, float bz, unsigned bs,
                                           int jbase,
                                           const int (&ii)[IPT],
                                           const float (&xi)[IPT],
                                           const float (&yi)[IPT],
                                           const float (&zi)[IPT],
                                           float (&mA)[IPT], float (&mB)[IPT],
                                           unsigned (&cA)[IPT], unsigned (&cB)[IPT]) {
#pragma unroll 8
    for (int l = 0; l < 64; l += 2) {
        float cx0 = bcast_f(bx, l), cy0 = bcast_f(by, l), cz0 = bcast_f(bz, l);
        unsigned s0 = __builtin_amdgcn_readlane(bs, l);
        const int j0 = jbase + l;
#pragma unroll
        for (int k = 0; k < IPT; ++k)
            do_pair<SELFCHK>(cx0, cy0, cz0, s0, j0, ii[k], xi[k], yi[k], zi[k], mA[k], cA[k]);
        float cx1 = bcast_f(bx, l + 1), cy1 = bcast_f(by, l + 1), cz1 = bcast_f(bz, l + 1);
        unsigned s1 = __builtin_amdgcn_readlane(bs, l + 1);
#pragma unroll
        for (int k = 0; k < IPT; ++k)
            do_pair<SELFCHK>(cx1, cy1, cz1, s1, j0 + 1, ii[k], xi[k], yi[k], zi[k], mB[k], cB[k]);
    }
}

// ---------------------------------------------------------------------------
// fused kernel: pair compute + last-block-per-group finalize + global fold.
// Group = (f, blockIdx.y): the 64 j-blocks covering the same 512 atoms.
// No spin-waits -- blocks that are not last simply exit (dispatch-order safe).
// ---------------------------------------------------------------------------
__global__ __launch_bounds__(BLK) void ns_fused_kernel(const float* __restrict__ coord,
                                                       const int* __restrict__ atype,
                                                       uint2* __restrict__ part,
                                                       int* __restrict__ counters,
                                                       int* __restrict__ pmax,
                                                       float* __restrict__ out,
                                                       int nloc) {
    const int f  = blockIdx.z;
    const int gy = blockIdx.y;
    const int q  = nloc / IPT;                    // 2048
    const int ib = gy * BLK;                      // [0, q)
    const int jbase = blockIdx.x * (nloc / NJ);   // 64-aligned

    const float* cf = coord + (size_t)f * nloc * 3;
    const int*   tf = atype + (size_t)f * nloc;

    // ---- load this block's 64-atom j-chunk into per-lane registers ----
    const int lane = threadIdx.x & 63;
    const int jl = jbase + lane;
    const float bx = cf[3 * jl], by = cf[3 * jl + 1], bz = cf[3 * jl + 2];
    const unsigned bs = 1u << (tf[jl] * 8);

    int ii[IPT];
    float xi[IPT], yi[IPT], zi[IPT];
    float mA[IPT], mB[IPT];
    unsigned cA[IPT], cB[IPT];
    bool ov = false;
#pragma unroll
    for (int k = 0; k < IPT; ++k) {
        const int base = ib + k * q;
        ii[k] = base + threadIdx.x;
        xi[k] = cf[3 * ii[k]];
        yi[k] = cf[3 * ii[k] + 1];
        zi[k] = cf[3 * ii[k] + 2];
        mA[k] = mB[k] = __builtin_inff();
        cA[k] = cB[k] = 0u;
        ov |= (jbase >= base) && (jbase < base + BLK);
    }

    if (ov)
        chunk_loop<true >(bx, by, bz, bs, jbase, ii, xi, yi, zi, mA, mB, cA, cB);
    else
        chunk_loop<false>(bx, by, bz, bs, jbase, ii, xi, yi, zi, mA, mB, cA, cB);

    const size_t pb = ((size_t)blockIdx.x * NFRAMES + f) * nloc;
#pragma unroll
    for (int k = 0; k < IPT; ++k)
        part[pb + ii[k]] = make_uint2(__float_as_uint(fminf(mA[k], mB[k])), cA[k] + cB[k]);

    // ---- group arrival: last block of (f,gy) finalizes the group ----
    __threadfence();                               // release partial stores
    const int ngroups = gridDim.y * gridDim.z;     // 16
    const int g = f * gridDim.y + gy;
    __shared__ int flag;
    if (threadIdx.x == 0) {
        int old = __hip_atomic_fetch_add(&counters[g], 1, __ATOMIC_ACQ_REL,
                                         __HIP_MEMORY_SCOPE_AGENT);
        flag = (old == (int)gridDim.x - 1);
    }
    __syncthreads();
    if (!flag) return;
    __threadfence();                               // acquire other blocks' stores

    // ---- finalize this group's atoms: reduce NJ partials per atom ----
    unsigned fcnt[IPT];
#pragma unroll
    for (int k = 0; k < IPT; ++k) {
        float ma = __builtin_inff(), mb = __builtin_inff();
        unsigned ca = 0u, cb = 0u;
#pragma unroll 8
        for (int j2 = 0; j2 < NJ; j2 += 2) {
            uint2 va = part[((size_t)j2 * NFRAMES + f) * nloc + ii[k]];
            uint2 vb = part[((size_t)(j2 + 1) * NFRAMES + f) * nloc + ii[k]];
            ma = fminf(ma, __uint_as_float(va.x));
            mb = fminf(mb, __uint_as_float(vb.x));
            ca += va.y;
            cb += vb.y;
        }
        out[(size_t)f * nloc + ii[k]] = fminf(ma, mb);
        fcnt[k] = ca + cb;
    }

    // ---- per-type max over the group's atoms ----
    int m0 = 0, m1 = 0, m2 = 0, m3 = 0;
#pragma unroll
    for (int k = 0; k < IPT; ++k) {
        const unsigned c = fcnt[k];
        m0 = max(m0, (int)(c & 255u));
        m1 = max(m1, (int)((c >> 8) & 255u));
        m2 = max(m2, (int)((c >> 16) & 255u));
        m3 = max(m3, (int)(c >> 24));
    }
    for (int off = 32; off > 0; off >>= 1) {
        m0 = max(m0, __shfl_xor(m0, off, 64));
        m1 = max(m1, __shfl_xor(m1, off, 64));
        m2 = max(m2, __shfl_xor(m2, off, 64));
        m3 = max(m3, __shfl_xor(m3, off, 64));
    }
    __shared__ int red[BLK / 64][NT];
    const int wid = threadIdx.x >> 6;
    if ((threadIdx.x & 63) == 0) {
        red[wid][0] = m0; red[wid][1] = m1; red[wid][2] = m2; red[wid][3] = m3;
    }
    __syncthreads();
    if (threadIdx.x < NT) {
        const int t = threadIdx.x;
        pmax[g * NT + t] = max(max(red[0][t], red[1][t]), max(red[2][t], red[3][t]));
    }

    // ---- global fold: last group writes the 8 output scalars ----
    __threadfence();                               // release pmax stores
    if (threadIdx.x == 0) {
        int old = __hip_atomic_fetch_add(&counters[ngroups], 1, __ATOMIC_ACQ_REL,
                                         __HIP_MEMORY_SCOPE_AGENT);
        flag = (old == ngroups - 1);
    }
    __syncthreads();
    if (!flag) return;
    __threadfence();                               // acquire all pmax
    if (threadIdx.x < NFRAMES * NT) {
        const int f2 = threadIdx.x / NT, t = threadIdx.x % NT;
        int m = 0;
        for (int gg = 0; gg < (int)gridDim.y; ++gg)
            m = max(m, pmax[(f2 * gridDim.y + gg) * NT + t]);
        out[(size_t)NFRAMES * nloc + f2 * NT + t] = (float)m;
    }
}

extern "C" void kernel_launch(void* const* d_in, const int* in_sizes, int n_in,
                              void* d_out, int out_size, void* d_ws, size_t ws_size,
                              hipStream_t stream) {
    const float* coord = (const float*)d_in[0];
    const int*   atype = (const int*)d_in[1];
    const int nloc = in_sizes[1] / NFRAMES;

    float* out = (float*)d_out;
    uint2* part = (uint2*)d_ws;                   // NJ * NFRAMES * nloc uint2
    const size_t part_bytes = (size_t)NJ * NFRAMES * nloc * sizeof(uint2);
    int* counters = (int*)((char*)d_ws + part_bytes);          // 17 ints
    int* pmax     = (int*)((char*)d_ws + part_bytes + 256);    // 16*NT ints

    // reset arrival counters every call (graph-capturable memset node)
    hipMemsetAsync(counters, 0, 256, stream);

    dim3 grid(NJ, nloc / (BLK * IPT), NFRAMES);
    ns_fused_kernel<<<grid, dim3(BLK), 0, stream>>>(coord, atype, part, counters,
                                                    pmax, out, nloc);
}

// Round 9
// 24.887 us; speedup vs baseline: 6.0776x; 6.0776x over previous
//
#include <hip/hip_runtime.h>
#include <stdint.h>

#define NFRAMES 2
#define NT 4           // NTYPES
#define BLK 256        // pair-kernel block size (4 waves)
#define NJ 64          // j-chunks: nloc/NJ = 64 atoms per tile
#define JT 64          // j-tile size (= nloc/NJ)
#define IPT 2          // atoms per thread in pair kernel
#define FBLK 64        // finalize block size (1 wave)

// ---------------------------------------------------------------------------
// one pair interaction; bit-exact r2 vs numpy ((dx^2+dy^2)+dz^2, no contract)
// ---------------------------------------------------------------------------
template <bool SELFCHK>
__device__ __forceinline__ void do_pair(float cx, float cy, float cz, unsigned sval,
                                        int j, int i,
                                        float xi, float yi, float zi,
                                        float& mm, unsigned& cc) {
#pragma clang fp contract(off)
    float dx = cx - xi;
    float dy = cy - yi;
    float dz = cz - zi;
    float xx = dx * dx;
    float yy = dy * dy;
    float zz = dz * dz;
    float r2 = (xx + yy) + zz;
    bool self = SELFCHK && (j == i);
    mm = fminf(mm, self ? __builtin_inff() : r2);
    bool near = (r2 < 36.0f) && !self;
    cc += near ? sval : 0u;
}

// ---------------------------------------------------------------------------
// inner loop over the LDS j-tile: wave-uniform ds_read_b128 = HW broadcast
// (no bank conflicts, no SGPR-write hazards). Two accumulator banks (l parity)
// give 2*IPT independent chains per thread.
// ---------------------------------------------------------------------------
template <bool SELFCHK>
__device__ __forceinline__ void tile_loop(const float4* __restrict__ sj, int jbase,
                                          const int (&ii)[IPT],
                                          const float (&xi)[IPT],
                                          const float (&yi)[IPT],
                                          const float (&zi)[IPT],
                                          float (&mA)[IPT], float (&mB)[IPT],
                                          unsigned (&cA)[IPT], unsigned (&cB)[IPT]) {
#pragma unroll 8
    for (int l = 0; l < JT; l += 2) {
        float4 c0 = sj[l];
        float4 c1 = sj[l + 1];
        const unsigned s0 = __float_as_uint(c0.w);
        const unsigned s1 = __float_as_uint(c1.w);
        const int j0 = jbase + l;
#pragma unroll
        for (int k = 0; k < IPT; ++k)
            do_pair<SELFCHK>(c0.x, c0.y, c0.z, s0, j0, ii[k], xi[k], yi[k], zi[k], mA[k], cA[k]);
#pragma unroll
        for (int k = 0; k < IPT; ++k)
            do_pair<SELFCHK>(c1.x, c1.y, c1.z, s1, j0 + 1, ii[k], xi[k], yi[k], zi[k], mB[k], cB[k]);
    }
}

// ---------------------------------------------------------------------------
// pair kernel: block stages a 64-atom j-tile into LDS (float4 x,y,z,svalbits),
// then each thread computes its IPT atoms against the tile, memory-free except
// broadcast LDS reads. Writes partial {min_bits, packed_cnt}; no atomics.
// Block (0,0,0) zeroes the 8 output tail slots for finalize's atomicMax.
// ---------------------------------------------------------------------------
__global__ __launch_bounds__(BLK) void ns_pair_kernel(const float* __restrict__ coord,
                                                      const int* __restrict__ atype,
                                                      uint2* __restrict__ part,
                                                      float* __restrict__ out,
                                                      int nloc) {
    const int f = blockIdx.z;
    const int q = nloc / IPT;                     // 2048
    const int ib = blockIdx.y * BLK;              // [0, q)
    const int jbase = blockIdx.x * JT;

    if (blockIdx.x == 0 && blockIdx.y == 0 && f == 0 && threadIdx.x < NFRAMES * NT)
        ((unsigned*)out)[(size_t)NFRAMES * nloc + threadIdx.x] = 0u;  // 0.0f bits

    const float* cf = coord + (size_t)f * nloc * 3;
    const int*   tf = atype + (size_t)f * nloc;

    __shared__ float4 sj[JT];
    if (threadIdx.x < JT) {
        const int jl = jbase + threadIdx.x;
        sj[threadIdx.x] = make_float4(cf[3 * jl], cf[3 * jl + 1], cf[3 * jl + 2],
                                      __uint_as_float(1u << (tf[jl] * 8)));
    }
    __syncthreads();

    int ii[IPT];
    float xi[IPT], yi[IPT], zi[IPT];
    float mA[IPT], mB[IPT];
    unsigned cA[IPT], cB[IPT];
    bool ov = false;
#pragma unroll
    for (int k = 0; k < IPT; ++k) {
        const int base = ib + k * q;
        ii[k] = base + threadIdx.x;
        xi[k] = cf[3 * ii[k]];
        yi[k] = cf[3 * ii[k] + 1];
        zi[k] = cf[3 * ii[k] + 2];
        mA[k] = mB[k] = __builtin_inff();
        cA[k] = cB[k] = 0u;
        ov |= (jbase >= base) && (jbase < base + BLK);   // 64-tile inside 256-range
    }

    if (ov)
        tile_loop<true >(sj, jbase, ii, xi, yi, zi, mA, mB, cA, cB);
    else
        tile_loop<false>(sj, jbase, ii, xi, yi, zi, mA, mB, cA, cB);

    const size_t pb = ((size_t)blockIdx.x * NFRAMES + f) * nloc;
#pragma unroll
    for (int k = 0; k < IPT; ++k)
        part[pb + ii[k]] = make_uint2(__float_as_uint(fminf(mA[k], mB[k])), cA[k] + cB[k]);
}

// ---------------------------------------------------------------------------
// finalize: one wave per 64 atoms; reduce NJ=64 partials per atom; write
// min_rr2; fold per-type count maxes into out tail via atomicMax on float
// bits (monotone for non-negative values).
// ---------------------------------------------------------------------------
__global__ __launch_bounds__(FBLK) void ns_finalize_kernel(const uint2* __restrict__ part,
                                                           float* __restrict__ out,
                                                           int nloc) {
    const int nbpf = nloc / FBLK;                 // 64 blocks per frame
    const int f = blockIdx.x / nbpf;
    const int i = (blockIdx.x % nbpf) * FBLK + threadIdx.x;

    float ma = __builtin_inff(), mb = __builtin_inff();
    unsigned cacc = 0u, cbacc = 0u;
#pragma unroll 16
    for (int jb = 0; jb < NJ; jb += 2) {
        uint2 va = part[((size_t)jb * NFRAMES + f) * nloc + i];
        uint2 vb = part[((size_t)(jb + 1) * NFRAMES + f) * nloc + i];
        ma = fminf(ma, __uint_as_float(va.x));
        mb = fminf(mb, __uint_as_float(vb.x));
        cacc += va.y;
        cbacc += vb.y;
    }
    out[(size_t)f * nloc + i] = fminf(ma, mb);
    const unsigned c = cacc + cbacc;

    int m0 = (int)(c & 255u);
    int m1 = (int)((c >> 8) & 255u);
    int m2 = (int)((c >> 16) & 255u);
    int m3 = (int)(c >> 24);
    for (int off = 32; off > 0; off >>= 1) {
        m0 = max(m0, __shfl_xor(m0, off, 64));
        m1 = max(m1, __shfl_xor(m1, off, 64));
        m2 = max(m2, __shfl_xor(m2, off, 64));
        m3 = max(m3, __shfl_xor(m3, off, 64));
    }
    if (threadIdx.x < NT) {
        const int t = threadIdx.x;
        const int mv = (t == 0) ? m0 : (t == 1) ? m1 : (t == 2) ? m2 : m3;
        atomicMax((unsigned*)out + (size_t)NFRAMES * nloc + f * NT + t,
                  __float_as_uint((float)mv));
    }
}

extern "C" void kernel_launch(void* const* d_in, const int* in_sizes, int n_in,
                              void* d_out, int out_size, void* d_ws, size_t ws_size,
                              hipStream_t stream) {
    const float* coord = (const float*)d_in[0];
    const int*   atype = (const int*)d_in[1];
    const int nloc = in_sizes[1] / NFRAMES;

    float* out  = (float*)d_out;
    uint2* part = (uint2*)d_ws;                   // NJ * NFRAMES * nloc uint2

    dim3 grid(NJ, nloc / (BLK * IPT), NFRAMES);
    ns_pair_kernel<<<grid, dim3(BLK), 0, stream>>>(coord, atype, part, out, nloc);

    const int nbpf = nloc / FBLK;
    ns_finalize_kernel<<<NFRAMES * nbpf, FBLK, 0, stream>>>(part, out, nloc);
}